// Round 1
// baseline (78.554 us; speedup 1.0000x reference)
//
#include <hip/hip_runtime.h>
#include <math.h>

#define NPART 8192
#define R2c   0.0025f     /* RADIUS^2 */
#define CR2c  0.01f       /* (2*RADIUS)^2 */
#define ACCS  0.005f
#define MAXV  0.05f
#define EPSV  1e-06f
#define NBLK  512         /* pair-kernel blocks: 8192 rows / 16 rows-per-block */
#define OUT_SCALARS 57344 /* offset of the 6 scalar outputs in d_out */

#define WRED(v) do { \
    v += __shfl_xor(v, 32); v += __shfl_xor(v, 16); v += __shfl_xor(v, 8); \
    v += __shfl_xor(v, 4);  v += __shfl_xor(v, 2);  v += __shfl_xor(v, 1); \
  } while (0)

// ---------------------------------------------------------------- prep ----
// Per row: pack pos (float2), y = x @ w_neigh (float4), cell flag (float).
__global__ __launch_bounds__(256) void prep_kernel(
    const float* __restrict__ x, const float* __restrict__ wn,
    float2* __restrict__ pos, float4* __restrict__ yv, float* __restrict__ cellf)
{
  int i = blockIdx.x * blockDim.x + threadIdx.x;
  if (i >= NPART) return;
  const float* xi = x + i * 7;
  float v0 = xi[0], v1 = xi[1], v2 = xi[2], v3 = xi[3];
  float v4 = xi[4], v5 = xi[5], v6 = xi[6];
  pos[i] = make_float2(v0, v1);
  float y[4];
#pragma unroll
  for (int c = 0; c < 4; ++c) {
    float s = v0 * wn[0 * 4 + c];
    s += v1 * wn[1 * 4 + c];
    s += v2 * wn[2 * 4 + c];
    s += v3 * wn[3 * 4 + c];
    s += v4 * wn[4 * 4 + c];
    s += v5 * wn[5 * 4 + c];
    s += v6 * wn[6 * 4 + c];
    y[c] = s;
  }
  yv[i] = make_float4(y[0], y[1], y[2], y[3]);
  cellf[i] = (v4 > 0.5f) ? 1.0f : 0.0f;
}

// ---------------------------------------------------------------- pairs ---
// One wave per 4 rows; lanes stride the 8192 j's. dist2 computed with
// explicit non-contracted mul/mul/add so the radius comparison matches the
// numpy reference bit-for-bit. Rare branch (d2 < consume-radius^2 for any of
// the 4 rows) loads y[j]/cell[j] under the exec mask.
#define ROWBODY(Rr, D2, NSX, NSY, NSZ, NSW, CONS, FOOD, CNB)                 \
  if ((D2) < CR2c && j != base + (Rr)) {                                     \
    CONS += cj;                                                              \
    if ((D2) < R2c) {                                                        \
      NSX += yj.x; NSY += yj.y; NSZ += yj.z; NSW += yj.w;                    \
      FOOD += fj; CNB += cj;                                                 \
    }                                                                        \
  }

#define EPI(Rr, NSX, NSY, NSZ, NSW, CONS, FOOD, CNB)                          \
  do {                                                                        \
    const int i = base + (Rr);                                                \
    const float* xi = x + i * 7;                                              \
    float px = xi[0], py = xi[1], vx = xi[2], vy = xi[3];                     \
    float typ = xi[4], x5 = xi[5], x6 = xi[6];                                \
    float ci = (typ > 0.5f) ? 1.0f : 0.0f;                                    \
    float h0 = bvec[0] + px * wself[0] + py * wself[4] + vx * wself[8] +      \
               vy * wself[12] + typ * wself[16] + x5 * wself[20] +            \
               x6 * wself[24] + NSX;                                          \
    float h1 = bvec[1] + px * wself[1] + py * wself[5] + vx * wself[9] +      \
               vy * wself[13] + typ * wself[17] + x5 * wself[21] +            \
               x6 * wself[25] + NSY;                                          \
    float h2 = bvec[2] + px * wself[2] + py * wself[6] + vx * wself[10] +     \
               vy * wself[14] + typ * wself[18] + x5 * wself[22] +            \
               x6 * wself[26] + NSZ;                                          \
    float h3 = bvec[3] + px * wself[3] + py * wself[7] + vx * wself[11] +     \
               vy * wself[15] + typ * wself[19] + x5 * wself[23] +            \
               x6 * wself[27] + NSW;                                          \
    float sc = ACCS * ci;                                                     \
    h0 *= sc; h1 *= sc; h2 *= sc; h3 *= sc;                                   \
    float nvx = fminf(fmaxf(vx + h0, -MAXV), MAXV);                           \
    float nvy = fminf(fmaxf(vy + h1, -MAXV), MAXV);                           \
    float npx = px + nvx, npy = py + nvy;                                     \
    float ax = fabsf(npx), ay = fabsf(npy);                                   \
    if (ax > 1.0f) border += logf(ax + EPSV);                                 \
    if (ay > 1.0f) border += logf(ay + EPSV);                                 \
    bool dead = (ci > 0.5f) && ((CNB) < 2.5f);                                \
    bool consumed = (ci < 0.5f) && ((CONS) > 4.5f);                           \
    float keep = (dead || consumed) ? 0.0f : 1.0f;                            \
    float* orow = out + i * 7;                                                \
    orow[0] = npx * keep; orow[1] = npy * keep;                               \
    orow[2] = nvx * keep; orow[3] = nvy * keep;                               \
    orow[4] = typ * keep; orow[5] = h2 * keep; orow[6] = h3 * keep;           \
    velbx += fabsf(nvx); velby += fabsf(nvy);                                 \
    if (consumed) foodr += 1.0f;                                              \
    if (dead) deadc += 1.0f;                                                  \
    visf += (FOOD);                                                           \
  } while (0)

__global__ __launch_bounds__(256) void pair_kernel(
    const float* __restrict__ x, const float* __restrict__ wself,
    const float* __restrict__ bvec, const float2* __restrict__ pos,
    const float4* __restrict__ yv, const float* __restrict__ cellf,
    float* __restrict__ out, float* __restrict__ partials)
{
  const int lane = threadIdx.x & 63;
  const int wave = threadIdx.x >> 6;
  const int base = (blockIdx.x * 4 + wave) * 4;

  const float2 pi0 = pos[base + 0];
  const float2 pi1 = pos[base + 1];
  const float2 pi2 = pos[base + 2];
  const float2 pi3 = pos[base + 3];

  float ns0x = 0.f, ns0y = 0.f, ns0z = 0.f, ns0w = 0.f;
  float ns1x = 0.f, ns1y = 0.f, ns1z = 0.f, ns1w = 0.f;
  float ns2x = 0.f, ns2y = 0.f, ns2z = 0.f, ns2w = 0.f;
  float ns3x = 0.f, ns3y = 0.f, ns3z = 0.f, ns3w = 0.f;
  float cons0 = 0.f, cons1 = 0.f, cons2 = 0.f, cons3 = 0.f;
  float food0 = 0.f, food1 = 0.f, food2 = 0.f, food3 = 0.f;
  float cnb0 = 0.f, cnb1 = 0.f, cnb2 = 0.f, cnb3 = 0.f;

  for (int j = lane; j < NPART; j += 64) {
    float2 pj = pos[j];
    float dx0 = __fsub_rn(pi0.x, pj.x), dy0 = __fsub_rn(pi0.y, pj.y);
    float dx1 = __fsub_rn(pi1.x, pj.x), dy1 = __fsub_rn(pi1.y, pj.y);
    float dx2 = __fsub_rn(pi2.x, pj.x), dy2 = __fsub_rn(pi2.y, pj.y);
    float dx3 = __fsub_rn(pi3.x, pj.x), dy3 = __fsub_rn(pi3.y, pj.y);
    float d20 = __fadd_rn(__fmul_rn(dx0, dx0), __fmul_rn(dy0, dy0));
    float d21 = __fadd_rn(__fmul_rn(dx1, dx1), __fmul_rn(dy1, dy1));
    float d22 = __fadd_rn(__fmul_rn(dx2, dx2), __fmul_rn(dy2, dy2));
    float d23 = __fadd_rn(__fmul_rn(dx3, dx3), __fmul_rn(dy3, dy3));
    if (d20 < CR2c || d21 < CR2c || d22 < CR2c || d23 < CR2c) {
      float cj = cellf[j];
      float4 yj = yv[j];
      float fj = 1.0f - cj;
      ROWBODY(0, d20, ns0x, ns0y, ns0z, ns0w, cons0, food0, cnb0)
      ROWBODY(1, d21, ns1x, ns1y, ns1z, ns1w, cons1, food1, cnb1)
      ROWBODY(2, d22, ns2x, ns2y, ns2z, ns2w, cons2, food2, cnb2)
      ROWBODY(3, d23, ns3x, ns3y, ns3z, ns3w, cons3, food3, cnb3)
    }
  }

  WRED(ns0x); WRED(ns0y); WRED(ns0z); WRED(ns0w);
  WRED(ns1x); WRED(ns1y); WRED(ns1z); WRED(ns1w);
  WRED(ns2x); WRED(ns2y); WRED(ns2z); WRED(ns2w);
  WRED(ns3x); WRED(ns3y); WRED(ns3z); WRED(ns3w);
  WRED(cons0); WRED(cons1); WRED(cons2); WRED(cons3);
  WRED(food0); WRED(food1); WRED(food2); WRED(food3);
  WRED(cnb0); WRED(cnb1); WRED(cnb2); WRED(cnb3);

  __shared__ float s_part[4][6];
  if (lane == 0) {
    float velbx = 0.f, velby = 0.f, border = 0.f;
    float foodr = 0.f, deadc = 0.f, visf = 0.f;
    EPI(0, ns0x, ns0y, ns0z, ns0w, cons0, food0, cnb0);
    EPI(1, ns1x, ns1y, ns1z, ns1w, cons1, food1, cnb1);
    EPI(2, ns2x, ns2y, ns2z, ns2w, cons2, food2, cnb2);
    EPI(3, ns3x, ns3y, ns3z, ns3w, cons3, food3, cnb3);
    s_part[wave][0] = velbx; s_part[wave][1] = velby; s_part[wave][2] = border;
    s_part[wave][3] = foodr; s_part[wave][4] = deadc; s_part[wave][5] = visf;
  }
  __syncthreads();
  if (threadIdx.x == 0) {
#pragma unroll
    for (int k = 0; k < 6; ++k) {
      partials[blockIdx.x * 6 + k] =
          s_part[0][k] + s_part[1][k] + s_part[2][k] + s_part[3][k];
    }
  }
}

// ------------------------------------------------------------- reduce -----
// Deterministic two-stage reduction: wave w reduces metric w over 512 block
// partials (fixed shuffle-tree order -> identical result every replay).
__global__ __launch_bounds__(384) void reduce_kernel(
    const float* __restrict__ partials, float* __restrict__ out)
{
  int wave = threadIdx.x >> 6, lane = threadIdx.x & 63;
  if (wave >= 6) return;
  float s = 0.f;
  for (int bidx = lane; bidx < NBLK; bidx += 64) s += partials[bidx * 6 + wave];
  WRED(s);
  if (lane == 0) {
    float v = s;
    if (wave < 2) v = s * (1.0f / 8192.0f); /* vel_bonus = mean */
    out[OUT_SCALARS + wave] = v;
  }
}

// ------------------------------------------------------------- launch -----
extern "C" void kernel_launch(void* const* d_in, const int* in_sizes, int n_in,
                              void* d_out, int out_size, void* d_ws, size_t ws_size,
                              hipStream_t stream)
{
  const float* x      = (const float*)d_in[0];
  const float* wself  = (const float*)d_in[1];
  const float* wneigh = (const float*)d_in[2];
  const float* bvec   = (const float*)d_in[3];
  float* out = (float*)d_out;
  float* ws  = (float*)d_ws;

  float2* pos   = (float2*)ws;                 /* 2N floats              */
  float4* yv    = (float4*)(ws + 2 * NPART);   /* 4N floats (16B align)  */
  float*  cellf = ws + 6 * NPART;              /* N floats               */
  float*  partials = ws + 7 * NPART;           /* NBLK*6 floats          */

  hipLaunchKernelGGL(prep_kernel, dim3(NPART / 256), dim3(256), 0, stream,
                     x, wneigh, pos, yv, cellf);
  hipLaunchKernelGGL(pair_kernel, dim3(NBLK), dim3(256), 0, stream,
                     x, wself, bvec, pos, yv, cellf, out, partials);
  hipLaunchKernelGGL(reduce_kernel, dim3(1), dim3(384), 0, stream,
                     partials, out);
}

// Round 2
// 44.684 us; speedup vs baseline: 1.7580x; 1.7580x over previous
//
#include <hip/hip_runtime.h>
#include <math.h>

#define NPART 8192
#define R2c   0.0025f     /* RADIUS^2 */
#define CR2c  0.01f       /* (2*RADIUS)^2 */
#define ACCS  0.005f
#define MAXV  0.05f
#define EPSV  1e-06f
#define NBLK  1024        /* pair-kernel blocks: 8192 rows / 8 rows-per-block */
#define OUT_SCALARS 57344 /* offset of the 6 scalar outputs in d_out */

#define WRED(v) do { \
    v += __shfl_xor(v, 32); v += __shfl_xor(v, 16); v += __shfl_xor(v, 8); \
    v += __shfl_xor(v, 4);  v += __shfl_xor(v, 2);  v += __shfl_xor(v, 1); \
  } while (0)

// ---------------------------------------------------------------- prep ----
// Per row: pack pos (float2), y = x @ w_neigh (float4), cell flag (float).
__global__ __launch_bounds__(256) void prep_kernel(
    const float* __restrict__ x, const float* __restrict__ wn,
    float2* __restrict__ pos, float4* __restrict__ yv, float* __restrict__ cellf)
{
  int i = blockIdx.x * blockDim.x + threadIdx.x;
  if (i >= NPART) return;
  const float* xi = x + i * 7;
  float v0 = xi[0], v1 = xi[1], v2 = xi[2], v3 = xi[3];
  float v4 = xi[4], v5 = xi[5], v6 = xi[6];
  pos[i] = make_float2(v0, v1);
  float y[4];
#pragma unroll
  for (int c = 0; c < 4; ++c) {
    float s = v0 * wn[0 * 4 + c];
    s += v1 * wn[1 * 4 + c];
    s += v2 * wn[2 * 4 + c];
    s += v3 * wn[3 * 4 + c];
    s += v4 * wn[4 * 4 + c];
    s += v5 * wn[5 * 4 + c];
    s += v6 * wn[6 * 4 + c];
    y[c] = s;
  }
  yv[i] = make_float4(y[0], y[1], y[2], y[3]);
  cellf[i] = (v4 > 0.5f) ? 1.0f : 0.0f;
}

// ---------------------------------------------------------------- pairs ---
// 2 rows per wave, 4 waves per block -> 4096 waves (4/SIMD) for latency
// hiding. Lanes stride j via float4 loads (2 positions per 16B), explicitly
// double-buffered so 2 loads are always in flight. Self-pair is INCLUDED in
// the hot loop (no j!=i test) and its exact contribution subtracted in the
// epilogue. dist2 uses explicit non-contracted mul/mul/add to match the
// numpy reference bit-for-bit at the radius comparisons.
#define PROCJ(PX_, PY_, J)                                                    \
  do {                                                                        \
    float dx0 = __fsub_rn(p0x, (PX_)), dy0 = __fsub_rn(p0y, (PY_));           \
    float dx1 = __fsub_rn(p1x, (PX_)), dy1 = __fsub_rn(p1y, (PY_));           \
    float d20 = __fadd_rn(__fmul_rn(dx0, dx0), __fmul_rn(dy0, dy0));          \
    float d21 = __fadd_rn(__fmul_rn(dx1, dx1), __fmul_rn(dy1, dy1));          \
    bool g0 = d20 < CR2c, g1 = d21 < CR2c;                                    \
    if (g0 || g1) {                                                           \
      float cj = cellf[(J)];                                                  \
      cons0 += g0 ? cj : 0.0f;                                                \
      cons1 += g1 ? cj : 0.0f;                                                \
      bool r0 = d20 < R2c, r1 = d21 < R2c;                                    \
      if (r0 || r1) {                                                         \
        float4 yj = yv[(J)];                                                  \
        cnt0 += r0 ? 1.0f : 0.0f;                                             \
        cnb0 += r0 ? cj : 0.0f;                                               \
        ns0x += r0 ? yj.x : 0.0f; ns0y += r0 ? yj.y : 0.0f;                   \
        ns0z += r0 ? yj.z : 0.0f; ns0w += r0 ? yj.w : 0.0f;                   \
        cnt1 += r1 ? 1.0f : 0.0f;                                             \
        cnb1 += r1 ? cj : 0.0f;                                               \
        ns1x += r1 ? yj.x : 0.0f; ns1y += r1 ? yj.y : 0.0f;                   \
        ns1z += r1 ? yj.z : 0.0f; ns1w += r1 ? yj.w : 0.0f;                   \
      }                                                                       \
    }                                                                         \
  } while (0)

#define EPI(Rr, NSX, NSY, NSZ, NSW, CONS, CNT, CNB)                           \
  do {                                                                        \
    const int i = base + (Rr);                                                \
    const float* xi = x + i * 7;                                              \
    float px = xi[0], py = xi[1], vx = xi[2], vy = xi[3];                     \
    float typ = xi[4], x5 = xi[5], x6 = xi[6];                                \
    float ci = (typ > 0.5f) ? 1.0f : 0.0f;                                    \
    float4 yi = yv[i];                                                        \
    float nsx = (NSX) - yi.x, nsy = (NSY) - yi.y;                             \
    float nsz = (NSZ) - yi.z, nsw = (NSW) - yi.w;                             \
    float consn = (CONS) - ci;                                                \
    float cnbn  = (CNB) - ci;                                                 \
    float cntn  = (CNT) - 1.0f;                                               \
    float foodv = cntn - cnbn;                                                \
    float h0 = bvec[0] + px * wself[0] + py * wself[4] + vx * wself[8] +      \
               vy * wself[12] + typ * wself[16] + x5 * wself[20] +            \
               x6 * wself[24] + nsx;                                          \
    float h1 = bvec[1] + px * wself[1] + py * wself[5] + vx * wself[9] +      \
               vy * wself[13] + typ * wself[17] + x5 * wself[21] +            \
               x6 * wself[25] + nsy;                                          \
    float h2 = bvec[2] + px * wself[2] + py * wself[6] + vx * wself[10] +     \
               vy * wself[14] + typ * wself[18] + x5 * wself[22] +            \
               x6 * wself[26] + nsz;                                          \
    float h3 = bvec[3] + px * wself[3] + py * wself[7] + vx * wself[11] +     \
               vy * wself[15] + typ * wself[19] + x5 * wself[23] +            \
               x6 * wself[27] + nsw;                                          \
    float sc = ACCS * ci;                                                     \
    h0 *= sc; h1 *= sc; h2 *= sc; h3 *= sc;                                   \
    float nvx = fminf(fmaxf(vx + h0, -MAXV), MAXV);                           \
    float nvy = fminf(fmaxf(vy + h1, -MAXV), MAXV);                           \
    float npx = px + nvx, npy = py + nvy;                                     \
    float ax = fabsf(npx), ay = fabsf(npy);                                   \
    if (ax > 1.0f) border += logf(ax + EPSV);                                 \
    if (ay > 1.0f) border += logf(ay + EPSV);                                 \
    bool dead = (ci > 0.5f) && (cnbn < 2.5f);                                 \
    bool consumed = (ci < 0.5f) && (consn > 4.5f);                            \
    float keep = (dead || consumed) ? 0.0f : 1.0f;                            \
    float* orow = out + i * 7;                                                \
    orow[0] = npx * keep; orow[1] = npy * keep;                               \
    orow[2] = nvx * keep; orow[3] = nvy * keep;                               \
    orow[4] = typ * keep; orow[5] = h2 * keep; orow[6] = h3 * keep;           \
    velbx += fabsf(nvx); velby += fabsf(nvy);                                 \
    if (consumed) foodr += 1.0f;                                              \
    if (dead) deadc += 1.0f;                                                  \
    visf += foodv;                                                            \
  } while (0)

__global__ __launch_bounds__(256) void pair_kernel(
    const float* __restrict__ x, const float* __restrict__ wself,
    const float* __restrict__ bvec, const float2* __restrict__ pos,
    const float4* __restrict__ yv, const float* __restrict__ cellf,
    float* __restrict__ out, float* __restrict__ partials)
{
  const int lane = threadIdx.x & 63;
  const int wave = threadIdx.x >> 6;
  const int base = blockIdx.x * 8 + wave * 2;

  const float2 pi0 = pos[base + 0];
  const float2 pi1 = pos[base + 1];
  const float p0x = pi0.x, p0y = pi0.y, p1x = pi1.x, p1y = pi1.y;

  float ns0x = 0.f, ns0y = 0.f, ns0z = 0.f, ns0w = 0.f;
  float ns1x = 0.f, ns1y = 0.f, ns1z = 0.f, ns1w = 0.f;
  float cons0 = 0.f, cons1 = 0.f;
  float cnt0 = 0.f, cnt1 = 0.f;
  float cnb0 = 0.f, cnb1 = 0.f;

  const float4* __restrict__ posq = (const float4*)pos; /* posq[k] = j 2k,2k+1 */
  float4 a = posq[lane];
  float4 b = posq[64 + lane];
  for (int it = 0; it < 32; ++it) {
    const int nbase = ((it + 1) & 31) * 128 + lane; /* wraps -> always valid */
    float4 na = posq[nbase];
    float4 nb = posq[nbase + 64];
    const int j0 = it * 256 + 2 * lane;
    PROCJ(a.x, a.y, j0);
    PROCJ(a.z, a.w, j0 + 1);
    PROCJ(b.x, b.y, j0 + 128);
    PROCJ(b.z, b.w, j0 + 129);
    a = na; b = nb;
  }

  WRED(ns0x); WRED(ns0y); WRED(ns0z); WRED(ns0w);
  WRED(ns1x); WRED(ns1y); WRED(ns1z); WRED(ns1w);
  WRED(cons0); WRED(cons1);
  WRED(cnt0); WRED(cnt1);
  WRED(cnb0); WRED(cnb1);

  __shared__ float s_part[4][6];
  if (lane == 0) {
    float velbx = 0.f, velby = 0.f, border = 0.f;
    float foodr = 0.f, deadc = 0.f, visf = 0.f;
    EPI(0, ns0x, ns0y, ns0z, ns0w, cons0, cnt0, cnb0);
    EPI(1, ns1x, ns1y, ns1z, ns1w, cons1, cnt1, cnb1);
    s_part[wave][0] = velbx; s_part[wave][1] = velby; s_part[wave][2] = border;
    s_part[wave][3] = foodr; s_part[wave][4] = deadc; s_part[wave][5] = visf;
  }
  __syncthreads();
  if (threadIdx.x == 0) {
#pragma unroll
    for (int k = 0; k < 6; ++k) {
      partials[blockIdx.x * 6 + k] =
          s_part[0][k] + s_part[1][k] + s_part[2][k] + s_part[3][k];
    }
  }
}

// ------------------------------------------------------------- reduce -----
// Deterministic two-stage reduction: wave w reduces metric w over NBLK block
// partials (fixed shuffle-tree order -> identical result every replay).
__global__ __launch_bounds__(384) void reduce_kernel(
    const float* __restrict__ partials, float* __restrict__ out)
{
  int wave = threadIdx.x >> 6, lane = threadIdx.x & 63;
  if (wave >= 6) return;
  float s = 0.f;
  for (int bidx = lane; bidx < NBLK; bidx += 64) s += partials[bidx * 6 + wave];
  WRED(s);
  if (lane == 0) {
    float v = s;
    if (wave < 2) v = s * (1.0f / 8192.0f); /* vel_bonus = mean */
    out[OUT_SCALARS + wave] = v;
  }
}

// ------------------------------------------------------------- launch -----
extern "C" void kernel_launch(void* const* d_in, const int* in_sizes, int n_in,
                              void* d_out, int out_size, void* d_ws, size_t ws_size,
                              hipStream_t stream)
{
  const float* x      = (const float*)d_in[0];
  const float* wself  = (const float*)d_in[1];
  const float* wneigh = (const float*)d_in[2];
  const float* bvec   = (const float*)d_in[3];
  float* out = (float*)d_out;
  float* ws  = (float*)d_ws;

  float2* pos   = (float2*)ws;                 /* 2N floats              */
  float4* yv    = (float4*)(ws + 2 * NPART);   /* 4N floats (16B align)  */
  float*  cellf = ws + 6 * NPART;              /* N floats               */
  float*  partials = ws + 7 * NPART;           /* NBLK*6 floats          */

  hipLaunchKernelGGL(prep_kernel, dim3(NPART / 256), dim3(256), 0, stream,
                     x, wneigh, pos, yv, cellf);
  hipLaunchKernelGGL(pair_kernel, dim3(NBLK), dim3(256), 0, stream,
                     x, wself, bvec, pos, yv, cellf, out, partials);
  hipLaunchKernelGGL(reduce_kernel, dim3(1), dim3(384), 0, stream,
                     partials, out);
}